// Round 7
// baseline (4254.948 us; speedup 1.0000x reference)
//
#include <hip/hip_runtime.h>

#define QLEN 128
#define WOUT 32
#define ROWS 4
#define PI_F 3.14159265358979f

// ---- bias/small-weight LDS offsets (floats) ----
#define OFF_BF    0      // 256
#define OFF_BIH   256    // 768
#define OFF_BHH   1024   // 768
#define OFF_LNG   1792   // 256
#define OFF_LNB   2048   // 256
#define OFF_BG    2304   // 64
#define OFF_BRP   2368   // 2
#define OFF_BIHR  2370   // 768
#define OFF_BHHR  3138   // 768
#define OFF_BRPR  3906   // 2
#define OFF_WRP   3908   // 512 (Wrp[2][256])
#define OFF_WRPR  4420   // 512
#define SB_TOTAL  4932

__device__ __forceinline__ float sigm(float x){ return 1.0f/(1.0f + __expf(-x)); }
__device__ __forceinline__ float tanh_f(float x){ return 2.0f/(1.0f + __expf(-2.0f*x)) - 1.0f; }

// LDS-only barrier: waits ds ops (cross-thread visibility) but leaves global
// loads in flight across the barrier (T4 counted-vmcnt idea; no cross-thread
// global communication exists in this kernel, so vmcnt need not drain).
__device__ __forceinline__ void barrier_lgkm(){
  asm volatile("s_waitcnt lgkmcnt(0)" ::: "memory");
  __builtin_amdgcn_s_barrier();
  asm volatile("" ::: "memory");
}

// Repack f32 W[N][K] (row-major) -> f32 T[k/4][N][4] so a wave's float4 weight
// loads (lane -> consecutive col c) are fully coalesced.
__global__ void transpose_w(const float* __restrict__ src, float* __restrict__ dst, int N, int K){
  int i = blockIdx.x*blockDim.x + threadIdx.x;
  if (i < N*K){
    int c = i / K; int k = i - c*K;
    dst[(size_t)(((k>>2)*N + c)<<2) + (k&3)] = src[i];
  }
}

__device__ __forceinline__ void fma4(float& acc, const float4& a, const float4& w){
  acc = fmaf(a.x, w.x, acc);
  acc = fmaf(a.y, w.y, acc);
  acc = fmaf(a.z, w.z, acc);
  acc = fmaf(a.w, w.w, acc);
}

__global__ __launch_bounds__(1024, 4) void knet_v7(
  const float* __restrict__ x_in,    // f32 [B][128][64]
  const float* __restrict__ t_wf,    // [48][256][4]
  const float* __restrict__ t_wih,   // [64][768][4]
  const float* __restrict__ t_whh,   // [64][768][4]
  const float* __restrict__ t_wg,    // [64][64][4]
  const float* __restrict__ t_wihr,  // [80][768][4]
  const float* __restrict__ t_whhr,  // [64][768][4]
  const float* __restrict__ p_bf,  const float* __restrict__ p_bih, const float* __restrict__ p_bhh,
  const float* __restrict__ p_lng, const float* __restrict__ p_lnb,
  const float* __restrict__ p_bg,  const float* __restrict__ p_wrp, const float* __restrict__ p_brp,
  const float* __restrict__ p_bihr,const float* __restrict__ p_bhhr,
  const float* __restrict__ p_wrpr,const float* __restrict__ p_brpr,
  float* __restrict__ out)           // f32 [B][32][64]
{
  __shared__ __align__(16) float sb[SB_TOTAL];
  __shared__ __align__(16) float s_h  [ROWS][260];   // post-LN h
  __shared__ __align__(16) float s_pre[ROWS][260];   // pre-LN GRU output
  __shared__ __align__(16) float s_zf [ROWS][260];
  __shared__ __align__(16) float s_feat[ROWS][196];
  __shared__ __align__(16) float s_x  [ROWS][64];
  __shared__ __align__(16) float s_part[4][6][ROWS][256];  // k-split partials
  __shared__ float s_rho[ROWS], s_phi[ROWS];

  const int tid = threadIdx.x;
  const int gb0 = blockIdx.x * ROWS;

  // ---- preload biases / tiny weights into LDS ----
  if (tid<256){ sb[OFF_BF+tid]=p_bf[tid]; sb[OFF_LNG+tid]=p_lng[tid]; sb[OFF_LNB+tid]=p_lnb[tid]; }
  if (tid<768){ sb[OFF_BIH+tid]=p_bih[tid]; sb[OFF_BHH+tid]=p_bhh[tid]; sb[OFF_BIHR+tid]=p_bihr[tid]; sb[OFF_BHHR+tid]=p_bhhr[tid]; }
  if (tid<64)  sb[OFF_BG+tid]=p_bg[tid];
  if (tid<512){ sb[OFF_WRP+tid]=p_wrp[tid]; sb[OFF_WRPR+tid]=p_wrpr[tid]; }
  if (tid<2){ sb[OFF_BRP+tid]=p_brp[tid]; sb[OFF_BRPR+tid]=p_brpr[tid]; }
  for (int e=tid; e<ROWS*256; e+=1024){ s_h[e>>8][e&255]=0.f; }

  const int w    = tid >> 6;    // wave id 0..15  (also kq for E phase)
  const int lane = tid & 63;
  const int g4   = tid >> 8;    // k-split group 0..3
  const int j256 = tid & 255;
  const int j6   = tid & 63;

  // persistent per-thread state (threads 0..255): row pr, component pd
  const int pr = tid >> 6;
  const int pd = tid & 63;
  float y_cur = 0.f, x_st = 0.f;
  if (tid < 256){
    y_cur = x_in[(size_t)(gb0+pr)*(QLEN*64) + pd];
    x_st  = y_cur;
    s_x[pr][pd] = x_st;
    s_feat[pr][pd] = 0.f; s_feat[pr][64+pd] = 0.f; s_feat[pr][128+pd] = 0.f;
  }

  const float4* tf  = (const float4*)t_wf;
  const float4* tih = (const float4*)t_wih;
  const float4* thh = (const float4*)t_whh;
  const float4* tg  = (const float4*)t_wg;
  const float4* tir = (const float4*)t_wihr;
  const float4* th2 = (const float4*)t_whhr;
  const int k0B = g4*12;   // B k-range start (K=192)
  const int k0C = g4*16;   // C k-range start (K=256)

  // ---- permanent register-cached weights (first k4 of each GEMM slice) ----
  const float4 pf_wf  = tf [k0B*256 + j256];
  const float4 pf_whr = thh[k0C*768 + j256];
  const float4 pf_whz = thh[k0C*768 + 256 + j256];
  const float4 pf_whn = thh[k0C*768 + 512 + j256];
  const float4 pc0 = tih[k0C*768 + j256];
  const float4 pc1 = tih[k0C*768 + 256 + j256];
  const float4 pc2 = tih[k0C*768 + 512 + j256];
  const float4 pe0 = tg[(w*4+0)*64 + j6];
  const float4 pe1 = tg[(w*4+1)*64 + j6];
  const float4 pe2 = tg[(w*4+2)*64 + j6];
  const float4 pe3 = tg[(w*4+3)*64 + j6];

  __syncthreads();

  // LayerNorm + readout-proj (rho/phi). reads s_pre, writes s_h, s_rho/s_phi. waves 0..3.
  auto ln_rp = [&](int wrpO, int brpO){
    if (w < ROWS){
      const int row = w;
      const int c0  = lane << 2;
      float4 v = *(const float4*)&s_pre[row][c0];
      float sum = v.x+v.y+v.z+v.w;
      float ss  = v.x*v.x + v.y*v.y + v.z*v.z + v.w*v.w;
      #pragma unroll
      for (int m=1;m<64;m<<=1){ sum += __shfl_xor(sum,m); ss += __shfl_xor(ss,m); }
      float mu = sum * (1.f/256.f);
      float rs = rsqrtf(ss*(1.f/256.f) - mu*mu + 1e-5f);
      float4 hn;
      hn.x = (v.x-mu)*rs*sb[OFF_LNG+c0  ] + sb[OFF_LNB+c0  ];
      hn.y = (v.y-mu)*rs*sb[OFF_LNG+c0+1] + sb[OFF_LNB+c0+1];
      hn.z = (v.z-mu)*rs*sb[OFF_LNG+c0+2] + sb[OFF_LNB+c0+2];
      hn.w = (v.w-mu)*rs*sb[OFF_LNG+c0+3] + sb[OFF_LNB+c0+3];
      *(float4*)&s_h[row][c0] = hn;
      float p0 = hn.x*sb[wrpO+c0] + hn.y*sb[wrpO+c0+1] + hn.z*sb[wrpO+c0+2] + hn.w*sb[wrpO+c0+3];
      float p1 = hn.x*sb[wrpO+256+c0] + hn.y*sb[wrpO+256+c0+1] + hn.z*sb[wrpO+256+c0+2] + hn.w*sb[wrpO+256+c0+3];
      #pragma unroll
      for (int m=1;m<64;m<<=1){ p0 += __shfl_xor(p0,m); p1 += __shfl_xor(p1,m); }
      if (lane==0){
        s_rho[row] = 1.25f * sigm(p0 + sb[brpO]);
        s_phi[row] = PI_F * tanh_f(p1 + sb[brpO+1]);
      }
    }
  };

  // ======================= ENCODER: 128 steps =======================
  #pragma unroll 1
  for (int t=0; t<QLEN; ++t){
    // issue next-y load early (consumed in P7)
    float y_next = 0.f;
    if (tid < 256){
      const int tn = (t+1<QLEN)? t+1 : QLEN-1;
      y_next = x_in[(size_t)(gb0+pr)*(QLEN*64) + (size_t)tn*64 + pd];
    }

    // ---- P1a: B partials (Wf x feat), peel k0B from registers ----
    {
      float a0,a1,a2,a3;
      {
        float4 f0=*(const float4*)&s_feat[0][k0B<<2];
        float4 f1=*(const float4*)&s_feat[1][k0B<<2];
        float4 f2=*(const float4*)&s_feat[2][k0B<<2];
        float4 f3=*(const float4*)&s_feat[3][k0B<<2];
        a0=0.f;a1=0.f;a2=0.f;a3=0.f;
        fma4(a0,f0,pf_wf); fma4(a1,f1,pf_wf); fma4(a2,f2,pf_wf); fma4(a3,f3,pf_wf);
      }
      #pragma unroll 2
      for (int k4=k0B+1;k4<k0B+12;k4++){
        float4 wv = tf[k4*256 + j256];
        float4 f0=*(const float4*)&s_feat[0][k4<<2];
        float4 f1=*(const float4*)&s_feat[1][k4<<2];
        float4 f2=*(const float4*)&s_feat[2][k4<<2];
        float4 f3=*(const float4*)&s_feat[3][k4<<2];
        fma4(a0,f0,wv); fma4(a1,f1,wv); fma4(a2,f2,wv); fma4(a3,f3,wv);
      }
      s_part[g4][0][0][j256]=a0; s_part[g4][0][1][j256]=a1;
      s_part[g4][0][2][j256]=a2; s_part[g4][0][3][j256]=a3;
    }
    // ---- P1b: C_h partials (Whh x h_old), peel k0C from registers ----
    {
      float a[3][ROWS];
      #pragma unroll
      for (int gg=0;gg<3;gg++){ a[gg][0]=0.f;a[gg][1]=0.f;a[gg][2]=0.f;a[gg][3]=0.f; }
      #pragma unroll
      for (int ri=0;ri<ROWS;ri++){
        float4 ah=*(const float4*)&s_h[ri][k0C<<2];
        fma4(a[0][ri],ah,pf_whr); fma4(a[1][ri],ah,pf_whz); fma4(a[2][ri],ah,pf_whn);
      }
      #pragma unroll 2
      for (int k4=k0C+1;k4<k0C+16;k4++){
        const int base=k4*768 + j256;
        float4 whr=thh[base], whz=thh[base+256], whn=thh[base+512];
        #pragma unroll
        for (int ri=0;ri<ROWS;ri++){
          float4 ah=*(const float4*)&s_h[ri][k4<<2];
          fma4(a[0][ri],ah,whr); fma4(a[1][ri],ah,whz); fma4(a[2][ri],ah,whn);
        }
      }
      #pragma unroll
      for (int gg=0;gg<3;gg++)
        #pragma unroll
        for (int ri=0;ri<ROWS;ri++)
          s_part[g4][3+gg][ri][j256]=a[gg][ri];
    }
    barrier_lgkm();

    // ---- P2: B finalize -> s_zf ----
    {
      const int r=tid>>8, jj=tid&255;
      s_zf[r][jj] = tanh_f(s_part[0][0][r][jj]+s_part[1][0][r][jj]
                          +s_part[2][0][r][jj]+s_part[3][0][r][jj] + sb[OFF_BF+jj]);
    }
    barrier_lgkm();

    // ---- P3: C_z partials (Wih x zf), peel k0C from registers ----
    {
      float a[3][ROWS];
      #pragma unroll
      for (int gg=0;gg<3;gg++){ a[gg][0]=0.f;a[gg][1]=0.f;a[gg][2]=0.f;a[gg][3]=0.f; }
      #pragma unroll
      for (int ri=0;ri<ROWS;ri++){
        float4 az=*(const float4*)&s_zf[ri][k0C<<2];
        fma4(a[0][ri],az,pc0); fma4(a[1][ri],az,pc1); fma4(a[2][ri],az,pc2);
      }
      #pragma unroll 2
      for (int k4=k0C+1;k4<k0C+16;k4++){
        const int base=k4*768 + j256;
        float4 wir=tih[base], wiz=tih[base+256], win=tih[base+512];
        #pragma unroll
        for (int ri=0;ri<ROWS;ri++){
          float4 az=*(const float4*)&s_zf[ri][k4<<2];
          fma4(a[0][ri],az,wir); fma4(a[1][ri],az,wiz); fma4(a[2][ri],az,win);
        }
      }
      #pragma unroll
      for (int gg=0;gg<3;gg++)
        #pragma unroll
        for (int ri=0;ri<ROWS;ri++)
          s_part[g4][gg][ri][j256]=a[gg][ri];
    }
    barrier_lgkm();

    // ---- P4: C finalize -> s_pre ----
    {
      const int r=tid>>8, jj=tid&255;
      float s0=s_part[0][0][r][jj]+s_part[1][0][r][jj]+s_part[2][0][r][jj]+s_part[3][0][r][jj];
      float s1=s_part[0][1][r][jj]+s_part[1][1][r][jj]+s_part[2][1][r][jj]+s_part[3][1][r][jj];
      float s2=s_part[0][2][r][jj]+s_part[1][2][r][jj]+s_part[2][2][r][jj]+s_part[3][2][r][jj];
      float s3=s_part[0][3][r][jj]+s_part[1][3][r][jj]+s_part[2][3][r][jj]+s_part[3][3][r][jj];
      float s4=s_part[0][4][r][jj]+s_part[1][4][r][jj]+s_part[2][4][r][jj]+s_part[3][4][r][jj];
      float s5=s_part[0][5][r][jj]+s_part[1][5][r][jj]+s_part[2][5][r][jj]+s_part[3][5][r][jj];
      float r_ = sigm(s0+sb[OFF_BIH+jj]     + s3+sb[OFF_BHH+jj]);
      float z_ = sigm(s1+sb[OFF_BIH+256+jj] + s4+sb[OFF_BHH+256+jj]);
      float n_ = tanh_f(s2+sb[OFF_BIH+512+jj] + r_*(s5+sb[OFF_BHH+512+jj]));
      s_pre[r][jj] = (1.f - z_)*n_ + z_*s_h[r][jj];
    }
    barrier_lgkm();

    // ---- P5: LayerNorm + rho/phi ----
    ln_rp(OFF_WRP, OFF_BRP);
    barrier_lgkm();

    // ---- P6: E partials (Wg x h_new), 16-way k-split, all from registers ----
    {
      float acc[ROWS]={0.f,0.f,0.f,0.f};
      const int kb = w*4;
      #pragma unroll
      for (int q=0;q<4;q++){
        float4 wv = (q==0)?pe0:(q==1)?pe1:(q==2)?pe2:pe3;
        #pragma unroll
        for (int ri=0;ri<ROWS;ri++){
          float4 ah=*(const float4*)&s_h[ri][(kb+q)<<2];
          fma4(acc[ri],ah,wv);
        }
      }
      #pragma unroll
      for (int ri=0;ri<ROWS;ri++) s_part[w>>2][0][ri][(w&3)*64 + j6] = acc[ri];
    }
    barrier_lgkm();

    // ---- P7: FA — K finalize + rotate + Kalman update + next feat ----
    if (tid < 256){
      float kacc = sb[OFF_BG+pd];
      #pragma unroll
      for (int q=0;q<16;q++) kacc += s_part[q>>2][0][pr][(q&3)*64+pd];
      float kg = sigm(kacc);
      float rho=s_rho[pr], phi=s_phi[pr];
      float sn,cs; __sincosf(phi,&sn,&cs);
      float px = __shfl_xor(x_st,32);
      float pre = (pd<32) ? rho*(cs*x_st - sn*px) : rho*(sn*px + cs*x_st);
      float del = kg*(y_cur - pre);
      x_st = pre + del;
      s_x[pr][pd] = x_st;
      s_feat[pr][pd]      = y_next - y_cur;
      s_feat[pr][64+pd]   = y_next - x_st;
      s_feat[pr][128+pd]  = del;
      y_cur = y_next;
    }
    barrier_lgkm();
  }

  // ======================= ROLLOUT: 32 steps =======================
  const int k0i = (g4<3)? g4*20 : 60;   // gi k-range start (K=320; k4<64 -> h, >=64 -> curr)
  const float4 pri0 = tir[k0i*768 + j256];
  const float4 pri1 = tir[k0i*768 + 256 + j256];
  const float4 pri2 = tir[k0i*768 + 512 + j256];
  const float4 prh0 = th2[k0C*768 + j256];
  const float4 prh1 = th2[k0C*768 + 256 + j256];
  const float4 prh2 = th2[k0C*768 + 512 + j256];

  #pragma unroll 1
  for (int u=0; u<WOUT; ++u){
    // ---- R-P1: all 6 gate partials ----
    {
      float a[6][ROWS];
      #pragma unroll
      for (int gg=0;gg<6;gg++){ a[gg][0]=0.f;a[gg][1]=0.f;a[gg][2]=0.f;a[gg][3]=0.f; }
      // gi peel (k0i < 64 for every g4 -> h activation)
      #pragma unroll
      for (int ri=0;ri<ROWS;ri++){
        float4 ah=*(const float4*)&s_h[ri][k0i<<2];
        fma4(a[0][ri],ah,pri0); fma4(a[1][ri],ah,pri1); fma4(a[2][ri],ah,pri2);
      }
      if (g4 < 3){
        #pragma unroll 2
        for (int k4=k0i+1;k4<k0i+20;k4++){
          const int base=k4*768 + j256;
          float4 wir=tir[base], wiz=tir[base+256], win=tir[base+512];
          #pragma unroll
          for (int ri=0;ri<ROWS;ri++){
            float4 ah=*(const float4*)&s_h[ri][k4<<2];
            fma4(a[0][ri],ah,wir); fma4(a[1][ri],ah,wiz); fma4(a[2][ri],ah,win);
          }
        }
      } else {
        #pragma unroll
        for (int k4=61;k4<64;k4++){
          const int base=k4*768 + j256;
          float4 wir=tir[base], wiz=tir[base+256], win=tir[base+512];
          #pragma unroll
          for (int ri=0;ri<ROWS;ri++){
            float4 ah=*(const float4*)&s_h[ri][k4<<2];
            fma4(a[0][ri],ah,wir); fma4(a[1][ri],ah,wiz); fma4(a[2][ri],ah,win);
          }
        }
        #pragma unroll 2
        for (int k4=64;k4<80;k4++){
          const int base=k4*768 + j256;
          float4 wir=tir[base], wiz=tir[base+256], win=tir[base+512];
          #pragma unroll
          for (int ri=0;ri<ROWS;ri++){
            float4 ax=*(const float4*)&s_x[ri][(k4-64)<<2];
            fma4(a[0][ri],ax,wir); fma4(a[1][ri],ax,wiz); fma4(a[2][ri],ax,win);
          }
        }
      }
      // gh peel + loop
      #pragma unroll
      for (int ri=0;ri<ROWS;ri++){
        float4 ah=*(const float4*)&s_h[ri][k0C<<2];
        fma4(a[3][ri],ah,prh0); fma4(a[4][ri],ah,prh1); fma4(a[5][ri],ah,prh2);
      }
      #pragma unroll 2
      for (int k4=k0C+1;k4<k0C+16;k4++){
        const int base=k4*768 + j256;
        float4 whr=th2[base], whz=th2[base+256], whn=th2[base+512];
        #pragma unroll
        for (int ri=0;ri<ROWS;ri++){
          float4 ah=*(const float4*)&s_h[ri][k4<<2];
          fma4(a[3][ri],ah,whr); fma4(a[4][ri],ah,whz); fma4(a[5][ri],ah,whn);
        }
      }
      #pragma unroll
      for (int gg=0;gg<6;gg++)
        #pragma unroll
        for (int ri=0;ri<ROWS;ri++)
          s_part[g4][gg][ri][j256]=a[gg][ri];
    }
    barrier_lgkm();

    // ---- R-P2: finalize -> s_pre ----
    {
      const int r=tid>>8, jj=tid&255;
      float s0=s_part[0][0][r][jj]+s_part[1][0][r][jj]+s_part[2][0][r][jj]+s_part[3][0][r][jj];
      float s1=s_part[0][1][r][jj]+s_part[1][1][r][jj]+s_part[2][1][r][jj]+s_part[3][1][r][jj];
      float s2=s_part[0][2][r][jj]+s_part[1][2][r][jj]+s_part[2][2][r][jj]+s_part[3][2][r][jj];
      float s3=s_part[0][3][r][jj]+s_part[1][3][r][jj]+s_part[2][3][r][jj]+s_part[3][3][r][jj];
      float s4=s_part[0][4][r][jj]+s_part[1][4][r][jj]+s_part[2][4][r][jj]+s_part[3][4][r][jj];
      float s5=s_part[0][5][r][jj]+s_part[1][5][r][jj]+s_part[2][5][r][jj]+s_part[3][5][r][jj];
      float r_ = sigm(s0+sb[OFF_BIHR+jj]     + s3+sb[OFF_BHHR+jj]);
      float z_ = sigm(s1+sb[OFF_BIHR+256+jj] + s4+sb[OFF_BHHR+256+jj]);
      float n_ = tanh_f(s2+sb[OFF_BIHR+512+jj] + r_*(s5+sb[OFF_BHHR+512+jj]));
      s_pre[r][jj] = (1.f - z_)*n_ + z_*s_h[r][jj];
    }
    barrier_lgkm();

    // ---- R-P3: LayerNorm + rho/phi ----
    ln_rp(OFF_WRPR, OFF_BRPR);
    barrier_lgkm();

    // ---- R-P4: rotate curr, emit ----
    if (tid < 256){
      float rho=s_rho[pr], phi=s_phi[pr];
      float sn,cs; __sincosf(phi,&sn,&cs);
      float px = __shfl_xor(x_st,32);
      float nx = (pd<32) ? rho*(cs*x_st - sn*px) : rho*(sn*px + cs*x_st);
      x_st = nx;
      s_x[pr][pd] = nx;
      out[(size_t)(gb0+pr)*(WOUT*64) + (size_t)u*64 + pd] = nx;
    }
    barrier_lgkm();
  }
}

extern "C" void kernel_launch(void* const* d_in, const int* in_sizes, int n_in,
                              void* d_out, int out_size, void* d_ws, size_t ws_size,
                              hipStream_t stream){
  const float* x_in = (const float*)d_in[0];
  // d_in[1] = w_out scalar (hardcoded 32)
  const float* Wf   = (const float*)d_in[2];
  const float* bf_  = (const float*)d_in[3];
  const float* Wih  = (const float*)d_in[4];
  const float* Whh  = (const float*)d_in[5];
  const float* bih  = (const float*)d_in[6];
  const float* bhh  = (const float*)d_in[7];
  const float* lng  = (const float*)d_in[8];
  const float* lnb  = (const float*)d_in[9];
  const float* Wg   = (const float*)d_in[10];
  const float* bg   = (const float*)d_in[11];
  const float* Wrp  = (const float*)d_in[12];
  const float* brp  = (const float*)d_in[13];
  const float* Wihr = (const float*)d_in[14];
  const float* Whhr = (const float*)d_in[15];
  const float* bihr = (const float*)d_in[16];
  const float* bhhr = (const float*)d_in[17];
  const float* Wrpr = (const float*)d_in[18];
  const float* brpr = (const float*)d_in[19];

  float* ws = (float*)d_ws;
  float* t_wf   = ws;             // 49152
  float* t_wih  = ws + 49152;     // 196608
  float* t_whh  = ws + 245760;    // 196608
  float* t_wg   = ws + 442368;    // 16384
  float* t_wihr = ws + 458752;    // 245760
  float* t_whhr = ws + 704512;    // 196608  (end: 901120 floats = 3.44 MB)

  transpose_w<<<(49152 +255)/256, 256, 0, stream>>>(Wf,   t_wf,   256, 192);
  transpose_w<<<(196608+255)/256, 256, 0, stream>>>(Wih,  t_wih,  768, 256);
  transpose_w<<<(196608+255)/256, 256, 0, stream>>>(Whh,  t_whh,  768, 256);
  transpose_w<<<(16384 +255)/256, 256, 0, stream>>>(Wg,   t_wg,   64,  256);
  transpose_w<<<(245760+255)/256, 256, 0, stream>>>(Wihr, t_wihr, 768, 320);
  transpose_w<<<(196608+255)/256, 256, 0, stream>>>(Whhr, t_whhr, 768, 256);

  knet_v7<<<256, 1024, 0, stream>>>(x_in, t_wf, t_wih, t_whh, t_wg, t_wihr, t_whhr,
      bf_, bih, bhh, lng, lnb, bg, Wrp, brp, bihr, bhhr, Wrpr, brpr,
      (float*)d_out);
}

// Round 8
// 3208.261 us; speedup vs baseline: 1.3262x; 1.3262x over previous
//
#include <hip/hip_runtime.h>

#define QLEN 128
#define WOUT 32
#define ROWS 4
#define PI_F 3.14159265358979f

// ---- bias/small-weight LDS offsets (floats) ----
#define OFF_BF    0      // 256
#define OFF_BIH   256    // 768
#define OFF_BHH   1024   // 768
#define OFF_LNG   1792   // 256
#define OFF_LNB   2048   // 256
#define OFF_BG    2304   // 64
#define OFF_BRP   2368   // 2
#define OFF_BIHR  2370   // 768
#define OFF_BHHR  3138   // 768
#define OFF_BRPR  3906   // 2
#define OFF_WRP   3908   // 512 (Wrp[2][256])
#define OFF_WRPR  4420   // 512
#define SB_TOTAL  4932

__device__ __forceinline__ float sigm(float x){ return 1.0f/(1.0f + __expf(-x)); }
__device__ __forceinline__ float tanh_f(float x){ return 2.0f/(1.0f + __expf(-2.0f*x)) - 1.0f; }

// LDS-only barrier: waits ds ops (cross-thread visibility) but leaves global
// loads in flight across the barrier (T4 idea; no cross-thread global
// communication exists in this kernel, so vmcnt need not drain).
__device__ __forceinline__ void barrier_lgkm(){
  asm volatile("s_waitcnt lgkmcnt(0)" ::: "memory");
  __builtin_amdgcn_s_barrier();
  asm volatile("" ::: "memory");
}

// Repack f32 W[N][K] (row-major) -> f32 T[k/4][N][4] so a wave's float4 weight
// loads (lane -> consecutive col c) are fully coalesced.
__global__ void transpose_w(const float* __restrict__ src, float* __restrict__ dst, int N, int K){
  int i = blockIdx.x*blockDim.x + threadIdx.x;
  if (i < N*K){
    int c = i / K; int k = i - c*K;
    dst[(size_t)(((k>>2)*N + c)<<2) + (k&3)] = src[i];
  }
}

__device__ __forceinline__ void fma4(float& acc, const float4& a, const float4& w){
  acc = fmaf(a.x, w.x, acc);
  acc = fmaf(a.y, w.y, acc);
  acc = fmaf(a.z, w.z, acc);
  acc = fmaf(a.w, w.w, acc);
}

__global__ __launch_bounds__(1024) void knet_v8(
  const float* __restrict__ x_in,    // f32 [B][128][64]
  const float* __restrict__ t_wf,    // [48][256][4]
  const float* __restrict__ t_wih,   // [64][768][4]
  const float* __restrict__ t_whh,   // [64][768][4]
  const float* __restrict__ t_wg,    // [64][64][4]
  const float* __restrict__ t_wihr,  // [80][768][4]
  const float* __restrict__ t_whhr,  // [64][768][4]
  const float* __restrict__ p_bf,  const float* __restrict__ p_bih, const float* __restrict__ p_bhh,
  const float* __restrict__ p_lng, const float* __restrict__ p_lnb,
  const float* __restrict__ p_bg,  const float* __restrict__ p_wrp, const float* __restrict__ p_brp,
  const float* __restrict__ p_bihr,const float* __restrict__ p_bhhr,
  const float* __restrict__ p_wrpr,const float* __restrict__ p_brpr,
  float* __restrict__ out)           // f32 [B][32][64]
{
  __shared__ __align__(16) float sb[SB_TOTAL];
  __shared__ __align__(16) float s_h  [ROWS][260];   // post-LN h
  __shared__ __align__(16) float s_pre[ROWS][260];   // pre-LN GRU output
  __shared__ __align__(16) float s_zf [ROWS][260];
  __shared__ __align__(16) float s_feat[ROWS][196];
  __shared__ __align__(16) float s_x  [ROWS][64];
  __shared__ __align__(16) float s_part[4][6][ROWS][256];  // k-split partials
  __shared__ float s_rho[ROWS], s_phi[ROWS];

  const int tid = threadIdx.x;
  const int gb0 = blockIdx.x * ROWS;

  // ---- preload biases / tiny weights into LDS ----
  if (tid<256){ sb[OFF_BF+tid]=p_bf[tid]; sb[OFF_LNG+tid]=p_lng[tid]; sb[OFF_LNB+tid]=p_lnb[tid]; }
  if (tid<768){ sb[OFF_BIH+tid]=p_bih[tid]; sb[OFF_BHH+tid]=p_bhh[tid]; sb[OFF_BIHR+tid]=p_bihr[tid]; sb[OFF_BHHR+tid]=p_bhhr[tid]; }
  if (tid<64)  sb[OFF_BG+tid]=p_bg[tid];
  if (tid<512){ sb[OFF_WRP+tid]=p_wrp[tid]; sb[OFF_WRPR+tid]=p_wrpr[tid]; }
  if (tid<2){ sb[OFF_BRP+tid]=p_brp[tid]; sb[OFF_BRPR+tid]=p_brpr[tid]; }
  for (int e=tid; e<ROWS*256; e+=1024){ s_h[e>>8][e&255]=0.f; }

  const int w    = tid >> 6;    // wave id 0..15
  const int lane = tid & 63;
  const int g4   = tid >> 8;    // k-split group 0..3
  const int j256 = tid & 255;
  const int j6   = tid & 63;

  // persistent per-thread state (threads 0..255): row pr, component pd
  const int pr = tid >> 6;
  const int pd = tid & 63;
  float y_cur = 0.f, x_st = 0.f;
  if (tid < 256){
    y_cur = x_in[(size_t)(gb0+pr)*(QLEN*64) + pd];
    x_st  = y_cur;
    s_x[pr][pd] = x_st;
    s_feat[pr][pd] = 0.f; s_feat[pr][64+pd] = 0.f; s_feat[pr][128+pd] = 0.f;
  }

  const float4* tf  = (const float4*)t_wf;
  const float4* tih = (const float4*)t_wih;
  const float4* thh = (const float4*)t_whh;
  const float4* tg  = (const float4*)t_wg;
  const float4* tir = (const float4*)t_wihr;
  const float4* th2 = (const float4*)t_whhr;
  const int k0B = g4*12;   // B k-range start (K=192)
  const int k0C = g4*16;   // C k-range start (K=256)

  __syncthreads();

  // LayerNorm + readout-proj (rho/phi). reads s_pre, writes s_h, s_rho/s_phi. waves 0..3.
  auto ln_rp = [&](int wrpO, int brpO){
    if (w < ROWS){
      const int row = w;
      const int c0  = lane << 2;
      float4 v = *(const float4*)&s_pre[row][c0];
      float sum = v.x+v.y+v.z+v.w;
      float ss  = v.x*v.x + v.y*v.y + v.z*v.z + v.w*v.w;
      #pragma unroll
      for (int m=1;m<64;m<<=1){ sum += __shfl_xor(sum,m); ss += __shfl_xor(ss,m); }
      float mu = sum * (1.f/256.f);
      float rs = rsqrtf(ss*(1.f/256.f) - mu*mu + 1e-5f);
      float4 hn;
      hn.x = (v.x-mu)*rs*sb[OFF_LNG+c0  ] + sb[OFF_LNB+c0  ];
      hn.y = (v.y-mu)*rs*sb[OFF_LNG+c0+1] + sb[OFF_LNB+c0+1];
      hn.z = (v.z-mu)*rs*sb[OFF_LNG+c0+2] + sb[OFF_LNB+c0+2];
      hn.w = (v.w-mu)*rs*sb[OFF_LNG+c0+3] + sb[OFF_LNB+c0+3];
      *(float4*)&s_h[row][c0] = hn;
      float p0 = hn.x*sb[wrpO+c0] + hn.y*sb[wrpO+c0+1] + hn.z*sb[wrpO+c0+2] + hn.w*sb[wrpO+c0+3];
      float p1 = hn.x*sb[wrpO+256+c0] + hn.y*sb[wrpO+256+c0+1] + hn.z*sb[wrpO+256+c0+2] + hn.w*sb[wrpO+256+c0+3];
      #pragma unroll
      for (int m=1;m<64;m<<=1){ p0 += __shfl_xor(p0,m); p1 += __shfl_xor(p1,m); }
      if (lane==0){
        s_rho[row] = 1.25f * sigm(p0 + sb[brpO]);
        s_phi[row] = PI_F * tanh_f(p1 + sb[brpO+1]);
      }
    }
  };

  // ======================= ENCODER: 128 steps =======================
  #pragma unroll 1
  for (int t=0; t<QLEN; ++t){
    // issue next-y load early (consumed in P7)
    float y_next = 0.f;
    if (tid < 256){
      const int tn = (t+1<QLEN)? t+1 : QLEN-1;
      y_next = x_in[(size_t)(gb0+pr)*(QLEN*64) + (size_t)tn*64 + pd];
    }

    // ---- P1a: B partials (Wf x feat) ----
    {
      float a0=0.f,a1=0.f,a2=0.f,a3=0.f;
      #pragma unroll 4
      for (int k4=k0B;k4<k0B+12;k4++){
        float4 wv = tf[k4*256 + j256];
        float4 f0=*(const float4*)&s_feat[0][k4<<2];
        float4 f1=*(const float4*)&s_feat[1][k4<<2];
        float4 f2=*(const float4*)&s_feat[2][k4<<2];
        float4 f3=*(const float4*)&s_feat[3][k4<<2];
        fma4(a0,f0,wv); fma4(a1,f1,wv); fma4(a2,f2,wv); fma4(a3,f3,wv);
      }
      s_part[g4][0][0][j256]=a0; s_part[g4][0][1][j256]=a1;
      s_part[g4][0][2][j256]=a2; s_part[g4][0][3][j256]=a3;
    }
    // ---- P1b: C_h partials (Whh x h_old) ----
    {
      float a[3][ROWS];
      #pragma unroll
      for (int gg=0;gg<3;gg++){ a[gg][0]=0.f;a[gg][1]=0.f;a[gg][2]=0.f;a[gg][3]=0.f; }
      #pragma unroll 2
      for (int k4=k0C;k4<k0C+16;k4++){
        const int base=k4*768 + j256;
        float4 whr=thh[base], whz=thh[base+256], whn=thh[base+512];
        #pragma unroll
        for (int ri=0;ri<ROWS;ri++){
          float4 ah=*(const float4*)&s_h[ri][k4<<2];
          fma4(a[0][ri],ah,whr); fma4(a[1][ri],ah,whz); fma4(a[2][ri],ah,whn);
        }
      }
      #pragma unroll
      for (int gg=0;gg<3;gg++)
        #pragma unroll
        for (int ri=0;ri<ROWS;ri++)
          s_part[g4][3+gg][ri][j256]=a[gg][ri];
    }
    barrier_lgkm();

    // ---- P2: B finalize -> s_zf ----
    {
      const int r=tid>>8, jj=tid&255;
      s_zf[r][jj] = tanh_f(s_part[0][0][r][jj]+s_part[1][0][r][jj]
                          +s_part[2][0][r][jj]+s_part[3][0][r][jj] + sb[OFF_BF+jj]);
    }
    barrier_lgkm();

    // ---- P3: C_z partials (Wih x zf) ----
    {
      float a[3][ROWS];
      #pragma unroll
      for (int gg=0;gg<3;gg++){ a[gg][0]=0.f;a[gg][1]=0.f;a[gg][2]=0.f;a[gg][3]=0.f; }
      #pragma unroll 4
      for (int k4=k0C;k4<k0C+16;k4++){
        const int base=k4*768 + j256;
        float4 wir=tih[base], wiz=tih[base+256], win=tih[base+512];
        #pragma unroll
        for (int ri=0;ri<ROWS;ri++){
          float4 az=*(const float4*)&s_zf[ri][k4<<2];
          fma4(a[0][ri],az,wir); fma4(a[1][ri],az,wiz); fma4(a[2][ri],az,win);
        }
      }
      #pragma unroll
      for (int gg=0;gg<3;gg++)
        #pragma unroll
        for (int ri=0;ri<ROWS;ri++)
          s_part[g4][gg][ri][j256]=a[gg][ri];
    }
    barrier_lgkm();

    // ---- P4: C finalize -> s_pre ----
    {
      const int r=tid>>8, jj=tid&255;
      float s0=s_part[0][0][r][jj]+s_part[1][0][r][jj]+s_part[2][0][r][jj]+s_part[3][0][r][jj];
      float s1=s_part[0][1][r][jj]+s_part[1][1][r][jj]+s_part[2][1][r][jj]+s_part[3][1][r][jj];
      float s2=s_part[0][2][r][jj]+s_part[1][2][r][jj]+s_part[2][2][r][jj]+s_part[3][2][r][jj];
      float s3=s_part[0][3][r][jj]+s_part[1][3][r][jj]+s_part[2][3][r][jj]+s_part[3][3][r][jj];
      float s4=s_part[0][4][r][jj]+s_part[1][4][r][jj]+s_part[2][4][r][jj]+s_part[3][4][r][jj];
      float s5=s_part[0][5][r][jj]+s_part[1][5][r][jj]+s_part[2][5][r][jj]+s_part[3][5][r][jj];
      float r_ = sigm(s0+sb[OFF_BIH+jj]     + s3+sb[OFF_BHH+jj]);
      float z_ = sigm(s1+sb[OFF_BIH+256+jj] + s4+sb[OFF_BHH+256+jj]);
      float n_ = tanh_f(s2+sb[OFF_BIH+512+jj] + r_*(s5+sb[OFF_BHH+512+jj]));
      s_pre[r][jj] = (1.f - z_)*n_ + z_*s_h[r][jj];
    }
    barrier_lgkm();

    // ---- P5: LayerNorm + rho/phi ----
    ln_rp(OFF_WRP, OFF_BRP);
    barrier_lgkm();

    // ---- P6: E partials (Wg x h_new), 16-way k-split ----
    {
      float acc[ROWS]={0.f,0.f,0.f,0.f};
      const int kb = w*4;
      #pragma unroll
      for (int q=0;q<4;q++){
        float4 wv = tg[(kb+q)*64 + j6];
        #pragma unroll
        for (int ri=0;ri<ROWS;ri++){
          float4 ah=*(const float4*)&s_h[ri][(kb+q)<<2];
          fma4(acc[ri],ah,wv);
        }
      }
      #pragma unroll
      for (int ri=0;ri<ROWS;ri++) s_part[w>>2][0][ri][(w&3)*64 + j6] = acc[ri];
    }
    barrier_lgkm();

    // ---- P7: FA — K finalize + rotate + Kalman update + next feat ----
    if (tid < 256){
      float kacc = sb[OFF_BG+pd];
      #pragma unroll
      for (int q=0;q<16;q++) kacc += s_part[q>>2][0][pr][(q&3)*64+pd];
      float kg = sigm(kacc);
      float rho=s_rho[pr], phi=s_phi[pr];
      float sn,cs; __sincosf(phi,&sn,&cs);
      float px = __shfl_xor(x_st,32);
      float pre = (pd<32) ? rho*(cs*x_st - sn*px) : rho*(sn*px + cs*x_st);
      float del = kg*(y_cur - pre);
      x_st = pre + del;
      s_x[pr][pd] = x_st;
      s_feat[pr][pd]      = y_next - y_cur;
      s_feat[pr][64+pd]   = y_next - x_st;
      s_feat[pr][128+pd]  = del;
      y_cur = y_next;
    }
    barrier_lgkm();
  }

  // ======================= ROLLOUT: 32 steps =======================
  #pragma unroll 1
  for (int u=0; u<WOUT; ++u){
    // ---- R-P1: all 6 gate partials ----
    {
      float a[6][ROWS];
      #pragma unroll
      for (int gg=0;gg<6;gg++){ a[gg][0]=0.f;a[gg][1]=0.f;a[gg][2]=0.f;a[gg][3]=0.f; }
      if (g4 < 3){
        const int k0i=g4*20;
        #pragma unroll 2
        for (int k4=k0i;k4<k0i+20;k4++){
          const int base=k4*768 + j256;
          float4 wir=tir[base], wiz=tir[base+256], win=tir[base+512];
          #pragma unroll
          for (int ri=0;ri<ROWS;ri++){
            float4 ah=*(const float4*)&s_h[ri][k4<<2];
            fma4(a[0][ri],ah,wir); fma4(a[1][ri],ah,wiz); fma4(a[2][ri],ah,win);
          }
        }
      } else {
        #pragma unroll
        for (int k4=60;k4<64;k4++){
          const int base=k4*768 + j256;
          float4 wir=tir[base], wiz=tir[base+256], win=tir[base+512];
          #pragma unroll
          for (int ri=0;ri<ROWS;ri++){
            float4 ah=*(const float4*)&s_h[ri][k4<<2];
            fma4(a[0][ri],ah,wir); fma4(a[1][ri],ah,wiz); fma4(a[2][ri],ah,win);
          }
        }
        #pragma unroll 2
        for (int k4=64;k4<80;k4++){
          const int base=k4*768 + j256;
          float4 wir=tir[base], wiz=tir[base+256], win=tir[base+512];
          #pragma unroll
          for (int ri=0;ri<ROWS;ri++){
            float4 ax=*(const float4*)&s_x[ri][(k4-64)<<2];
            fma4(a[0][ri],ax,wir); fma4(a[1][ri],ax,wiz); fma4(a[2][ri],ax,win);
          }
        }
      }
      {
        #pragma unroll 2
        for (int k4=k0C;k4<k0C+16;k4++){
          const int base=k4*768 + j256;
          float4 whr=th2[base], whz=th2[base+256], whn=th2[base+512];
          #pragma unroll
          for (int ri=0;ri<ROWS;ri++){
            float4 ah=*(const float4*)&s_h[ri][k4<<2];
            fma4(a[3][ri],ah,whr); fma4(a[4][ri],ah,whz); fma4(a[5][ri],ah,whn);
          }
        }
      }
      #pragma unroll
      for (int gg=0;gg<6;gg++)
        #pragma unroll
        for (int ri=0;ri<ROWS;ri++)
          s_part[g4][gg][ri][j256]=a[gg][ri];
    }
    barrier_lgkm();

    // ---- R-P2: finalize -> s_pre ----
    {
      const int r=tid>>8, jj=tid&255;
      float s0=s_part[0][0][r][jj]+s_part[1][0][r][jj]+s_part[2][0][r][jj]+s_part[3][0][r][jj];
      float s1=s_part[0][1][r][jj]+s_part[1][1][r][jj]+s_part[2][1][r][jj]+s_part[3][1][r][jj];
      float s2=s_part[0][2][r][jj]+s_part[1][2][r][jj]+s_part[2][2][r][jj]+s_part[3][2][r][jj];
      float s3=s_part[0][3][r][jj]+s_part[1][3][r][jj]+s_part[2][3][r][jj]+s_part[3][3][r][jj];
      float s4=s_part[0][4][r][jj]+s_part[1][4][r][jj]+s_part[2][4][r][jj]+s_part[3][4][r][jj];
      float s5=s_part[0][5][r][jj]+s_part[1][5][r][jj]+s_part[2][5][r][jj]+s_part[3][5][r][jj];
      float r_ = sigm(s0+sb[OFF_BIHR+jj]     + s3+sb[OFF_BHHR+jj]);
      float z_ = sigm(s1+sb[OFF_BIHR+256+jj] + s4+sb[OFF_BHHR+256+jj]);
      float n_ = tanh_f(s2+sb[OFF_BIHR+512+jj] + r_*(s5+sb[OFF_BHHR+512+jj]));
      s_pre[r][jj] = (1.f - z_)*n_ + z_*s_h[r][jj];
    }
    barrier_lgkm();

    // ---- R-P3: LayerNorm + rho/phi ----
    ln_rp(OFF_WRPR, OFF_BRPR);
    barrier_lgkm();

    // ---- R-P4: rotate curr, emit ----
    if (tid < 256){
      float rho=s_rho[pr], phi=s_phi[pr];
      float sn,cs; __sincosf(phi,&sn,&cs);
      float px = __shfl_xor(x_st,32);
      float nx = (pd<32) ? rho*(cs*x_st - sn*px) : rho*(sn*px + cs*x_st);
      x_st = nx;
      s_x[pr][pd] = nx;
      out[(size_t)(gb0+pr)*(WOUT*64) + (size_t)u*64 + pd] = nx;
    }
    barrier_lgkm();
  }
}

extern "C" void kernel_launch(void* const* d_in, const int* in_sizes, int n_in,
                              void* d_out, int out_size, void* d_ws, size_t ws_size,
                              hipStream_t stream){
  const float* x_in = (const float*)d_in[0];
  // d_in[1] = w_out scalar (hardcoded 32)
  const float* Wf   = (const float*)d_in[2];
  const float* bf_  = (const float*)d_in[3];
  const float* Wih  = (const float*)d_in[4];
  const float* Whh  = (const float*)d_in[5];
  const float* bih  = (const float*)d_in[6];
  const float* bhh  = (const float*)d_in[7];
  const float* lng  = (const float*)d_in[8];
  const float* lnb  = (const float*)d_in[9];
  const float* Wg   = (const float*)d_in[10];
  const float* bg   = (const float*)d_in[11];
  const float* Wrp  = (const float*)d_in[12];
  const float* brp  = (const float*)d_in[13];
  const float* Wihr = (const float*)d_in[14];
  const float* Whhr = (const float*)d_in[15];
  const float* bihr = (const float*)d_in[16];
  const float* bhhr = (const float*)d_in[17];
  const float* Wrpr = (const float*)d_in[18];
  const float* brpr = (const float*)d_in[19];

  float* ws = (float*)d_ws;
  float* t_wf   = ws;             // 49152
  float* t_wih  = ws + 49152;     // 196608
  float* t_whh  = ws + 245760;    // 196608
  float* t_wg   = ws + 442368;    // 16384
  float* t_wihr = ws + 458752;    // 245760
  float* t_whhr = ws + 704512;    // 196608  (end: 901120 floats = 3.44 MB)

  transpose_w<<<(49152 +255)/256, 256, 0, stream>>>(Wf,   t_wf,   256, 192);
  transpose_w<<<(196608+255)/256, 256, 0, stream>>>(Wih,  t_wih,  768, 256);
  transpose_w<<<(196608+255)/256, 256, 0, stream>>>(Whh,  t_whh,  768, 256);
  transpose_w<<<(16384 +255)/256, 256, 0, stream>>>(Wg,   t_wg,   64,  256);
  transpose_w<<<(245760+255)/256, 256, 0, stream>>>(Wihr, t_wihr, 768, 320);
  transpose_w<<<(196608+255)/256, 256, 0, stream>>>(Whhr, t_whhr, 768, 256);

  knet_v8<<<256, 1024, 0, stream>>>(x_in, t_wf, t_wih, t_whh, t_wg, t_wihr, t_whhr,
      bf_, bih, bhh, lng, lnb, bg, Wrp, brp, bihr, bhhr, Wrpr, brpr,
      (float*)d_out);
}

// Round 9
// 2984.358 us; speedup vs baseline: 1.4257x; 1.0750x over previous
//
#include <hip/hip_runtime.h>

#define QLEN 128
#define WOUT 32
#define ROWS 4
#define PI_F 3.14159265358979f

typedef __attribute__((ext_vector_type(2))) float f32x2;

// ---- bias/small-weight LDS offsets (floats) ----
#define OFF_BF    0      // 256
#define OFF_BIH   256    // 768
#define OFF_BHH   1024   // 768
#define OFF_LNG   1792   // 256
#define OFF_LNB   2048   // 256
#define OFF_BG    2304   // 64
#define OFF_BRP   2368   // 2
#define OFF_BIHR  2370   // 768
#define OFF_BHHR  3138   // 768
#define OFF_BRPR  3906   // 2
#define OFF_WRP   3908   // 512 (Wrp[2][256])
#define OFF_WRPR  4420   // 512
#define SB_TOTAL  4932

__device__ __forceinline__ float sigm(float x){ return 1.0f/(1.0f + __expf(-x)); }
__device__ __forceinline__ float tanh_f(float x){ return 2.0f/(1.0f + __expf(-2.0f*x)) - 1.0f; }

// LDS-only barrier: waits ds ops but leaves global loads in flight (T4 idea).
__device__ __forceinline__ void barrier_lgkm(){
  asm volatile("s_waitcnt lgkmcnt(0)" ::: "memory");
  __builtin_amdgcn_s_barrier();
  asm volatile("" ::: "memory");
}

// packed 2xf32 FMA: acc.xy += a.xy * b.xy  (one VALU issue for 2 MACs)
__device__ __forceinline__ void pkfma(f32x2& acc, f32x2 a, f32x2 b){
  asm("v_pk_fma_f32 %0, %1, %2, %0" : "+v"(acc) : "v"(a), "v"(b));
}
// dot-step of a float4 pair into a packed accumulator (2 instructions, 8 MACs... 4 MACs)
__device__ __forceinline__ void fma4p(f32x2& acc, const float4& a, const float4& w){
  f32x2 alo = {a.x, a.y}, ahi = {a.z, a.w};
  f32x2 wlo = {w.x, w.y}, whi = {w.z, w.w};
  pkfma(acc, alo, wlo); pkfma(acc, ahi, whi);
}
__device__ __forceinline__ float hadd(f32x2 v){ return v[0] + v[1]; }

// Repack f32 W[N][K] (row-major) -> f32 T[k/4][N][4] so a wave's float4 weight
// loads (lane -> consecutive col c) are fully coalesced.
__global__ void transpose_w(const float* __restrict__ src, float* __restrict__ dst, int N, int K){
  int i = blockIdx.x*blockDim.x + threadIdx.x;
  if (i < N*K){
    int c = i / K; int k = i - c*K;
    dst[(size_t)(((k>>2)*N + c)<<2) + (k&3)] = src[i];
  }
}

__global__ __launch_bounds__(1024) void knet_v9(
  const float* __restrict__ x_in,    // f32 [B][128][64]
  const float* __restrict__ t_wf,    // [48][256][4]
  const float* __restrict__ t_wih,   // [64][768][4]
  const float* __restrict__ t_whh,   // [64][768][4]
  const float* __restrict__ t_wg,    // [64][64][4]
  const float* __restrict__ t_wihr,  // [80][768][4]
  const float* __restrict__ t_whhr,  // [64][768][4]
  const float* __restrict__ p_bf,  const float* __restrict__ p_bih, const float* __restrict__ p_bhh,
  const float* __restrict__ p_lng, const float* __restrict__ p_lnb,
  const float* __restrict__ p_bg,  const float* __restrict__ p_wrp, const float* __restrict__ p_brp,
  const float* __restrict__ p_bihr,const float* __restrict__ p_bhhr,
  const float* __restrict__ p_wrpr,const float* __restrict__ p_brpr,
  float* __restrict__ out)           // f32 [B][32][64]
{
  __shared__ __align__(16) float sb[SB_TOTAL];
  __shared__ __align__(16) float s_h  [ROWS][260];   // post-LN h
  __shared__ __align__(16) float s_pre[ROWS][260];   // pre-LN GRU output
  __shared__ __align__(16) float s_zf [ROWS][260];
  __shared__ __align__(16) float s_feat[ROWS][196];
  __shared__ __align__(16) float s_x  [ROWS][64];
  __shared__ __align__(16) float s_part[4][6][ROWS][256];  // k-split partials
  __shared__ float s_rho[ROWS], s_phi[ROWS];

  const int tid = threadIdx.x;
  const int gb0 = blockIdx.x * ROWS;

  // ---- preload biases / tiny weights into LDS ----
  if (tid<256){ sb[OFF_BF+tid]=p_bf[tid]; sb[OFF_LNG+tid]=p_lng[tid]; sb[OFF_LNB+tid]=p_lnb[tid]; }
  if (tid<768){ sb[OFF_BIH+tid]=p_bih[tid]; sb[OFF_BHH+tid]=p_bhh[tid]; sb[OFF_BIHR+tid]=p_bihr[tid]; sb[OFF_BHHR+tid]=p_bhhr[tid]; }
  if (tid<64)  sb[OFF_BG+tid]=p_bg[tid];
  if (tid<512){ sb[OFF_WRP+tid]=p_wrp[tid]; sb[OFF_WRPR+tid]=p_wrpr[tid]; }
  if (tid<2){ sb[OFF_BRP+tid]=p_brp[tid]; sb[OFF_BRPR+tid]=p_brpr[tid]; }
  for (int e=tid; e<ROWS*256; e+=1024){ s_h[e>>8][e&255]=0.f; }

  const int w    = tid >> 6;    // wave id 0..15
  const int lane = tid & 63;
  const int g4   = tid >> 8;    // k-split group 0..3
  const int j256 = tid & 255;
  const int j6   = tid & 63;

  // persistent per-thread state (threads 0..255): row pr, component pd
  const int pr = tid >> 6;
  const int pd = tid & 63;
  float y_cur = 0.f, x_st = 0.f;
  if (tid < 256){
    y_cur = x_in[(size_t)(gb0+pr)*(QLEN*64) + pd];
    x_st  = y_cur;
    s_x[pr][pd] = x_st;
    s_feat[pr][pd] = 0.f; s_feat[pr][64+pd] = 0.f; s_feat[pr][128+pd] = 0.f;
  }

  const float4* tf  = (const float4*)t_wf;
  const float4* tih = (const float4*)t_wih;
  const float4* thh = (const float4*)t_whh;
  const float4* tg  = (const float4*)t_wg;
  const float4* tir = (const float4*)t_wihr;
  const float4* th2 = (const float4*)t_whhr;
  const int k0B = g4*12;   // B k-range start (K=192)
  const int k0C = g4*16;   // C k-range start (K=256)

  __syncthreads();

  // LayerNorm + readout-proj (rho/phi). reads s_pre, writes s_h, s_rho/s_phi. waves 0..3.
  auto ln_rp = [&](int wrpO, int brpO){
    if (w < ROWS){
      const int row = w;
      const int c0  = lane << 2;
      float4 v = *(const float4*)&s_pre[row][c0];
      float sum = v.x+v.y+v.z+v.w;
      float ss  = v.x*v.x + v.y*v.y + v.z*v.z + v.w*v.w;
      #pragma unroll
      for (int m=1;m<64;m<<=1){ sum += __shfl_xor(sum,m); ss += __shfl_xor(ss,m); }
      float mu = sum * (1.f/256.f);
      float rs = rsqrtf(ss*(1.f/256.f) - mu*mu + 1e-5f);
      float4 hn;
      hn.x = (v.x-mu)*rs*sb[OFF_LNG+c0  ] + sb[OFF_LNB+c0  ];
      hn.y = (v.y-mu)*rs*sb[OFF_LNG+c0+1] + sb[OFF_LNB+c0+1];
      hn.z = (v.z-mu)*rs*sb[OFF_LNG+c0+2] + sb[OFF_LNB+c0+2];
      hn.w = (v.w-mu)*rs*sb[OFF_LNG+c0+3] + sb[OFF_LNB+c0+3];
      *(float4*)&s_h[row][c0] = hn;
      float p0 = hn.x*sb[wrpO+c0] + hn.y*sb[wrpO+c0+1] + hn.z*sb[wrpO+c0+2] + hn.w*sb[wrpO+c0+3];
      float p1 = hn.x*sb[wrpO+256+c0] + hn.y*sb[wrpO+256+c0+1] + hn.z*sb[wrpO+256+c0+2] + hn.w*sb[wrpO+256+c0+3];
      #pragma unroll
      for (int m=1;m<64;m<<=1){ p0 += __shfl_xor(p0,m); p1 += __shfl_xor(p1,m); }
      if (lane==0){
        s_rho[row] = 1.25f * sigm(p0 + sb[brpO]);
        s_phi[row] = PI_F * tanh_f(p1 + sb[brpO+1]);
      }
    }
  };

  // ======================= ENCODER: 128 steps =======================
  #pragma unroll 1
  for (int t=0; t<QLEN; ++t){
    // issue next-y load early (consumed in P7)
    float y_next = 0.f;
    if (tid < 256){
      const int tn = (t+1<QLEN)? t+1 : QLEN-1;
      y_next = x_in[(size_t)(gb0+pr)*(QLEN*64) + (size_t)tn*64 + pd];
    }

    // ---- P1a: B partials (Wf x feat) ----
    {
      f32x2 a0={0.f,0.f},a1={0.f,0.f},a2={0.f,0.f},a3={0.f,0.f};
      #pragma unroll 4
      for (int k4=k0B;k4<k0B+12;k4++){
        float4 wv = tf[k4*256 + j256];
        float4 f0=*(const float4*)&s_feat[0][k4<<2];
        float4 f1=*(const float4*)&s_feat[1][k4<<2];
        float4 f2=*(const float4*)&s_feat[2][k4<<2];
        float4 f3=*(const float4*)&s_feat[3][k4<<2];
        fma4p(a0,f0,wv); fma4p(a1,f1,wv); fma4p(a2,f2,wv); fma4p(a3,f3,wv);
      }
      s_part[g4][0][0][j256]=hadd(a0); s_part[g4][0][1][j256]=hadd(a1);
      s_part[g4][0][2][j256]=hadd(a2); s_part[g4][0][3][j256]=hadd(a3);
    }
    // ---- P1b: C_h partials (Whh x h_old) ----
    {
      f32x2 a[3][ROWS];
      #pragma unroll
      for (int gg=0;gg<3;gg++)
        #pragma unroll
        for (int ri=0;ri<ROWS;ri++) a[gg][ri]=(f32x2){0.f,0.f};
      #pragma unroll 2
      for (int k4=k0C;k4<k0C+16;k4++){
        const int base=k4*768 + j256;
        float4 whr=thh[base], whz=thh[base+256], whn=thh[base+512];
        #pragma unroll
        for (int ri=0;ri<ROWS;ri++){
          float4 ah=*(const float4*)&s_h[ri][k4<<2];
          fma4p(a[0][ri],ah,whr); fma4p(a[1][ri],ah,whz); fma4p(a[2][ri],ah,whn);
        }
      }
      #pragma unroll
      for (int gg=0;gg<3;gg++)
        #pragma unroll
        for (int ri=0;ri<ROWS;ri++)
          s_part[g4][3+gg][ri][j256]=hadd(a[gg][ri]);
    }
    barrier_lgkm();

    // ---- P2: B finalize -> s_zf ----
    {
      const int r=tid>>8, jj=tid&255;
      s_zf[r][jj] = tanh_f(s_part[0][0][r][jj]+s_part[1][0][r][jj]
                          +s_part[2][0][r][jj]+s_part[3][0][r][jj] + sb[OFF_BF+jj]);
    }
    barrier_lgkm();

    // ---- P3: C_z partials (Wih x zf) ----
    {
      f32x2 a[3][ROWS];
      #pragma unroll
      for (int gg=0;gg<3;gg++)
        #pragma unroll
        for (int ri=0;ri<ROWS;ri++) a[gg][ri]=(f32x2){0.f,0.f};
      #pragma unroll 4
      for (int k4=k0C;k4<k0C+16;k4++){
        const int base=k4*768 + j256;
        float4 wir=tih[base], wiz=tih[base+256], win=tih[base+512];
        #pragma unroll
        for (int ri=0;ri<ROWS;ri++){
          float4 az=*(const float4*)&s_zf[ri][k4<<2];
          fma4p(a[0][ri],az,wir); fma4p(a[1][ri],az,wiz); fma4p(a[2][ri],az,win);
        }
      }
      #pragma unroll
      for (int gg=0;gg<3;gg++)
        #pragma unroll
        for (int ri=0;ri<ROWS;ri++)
          s_part[g4][gg][ri][j256]=hadd(a[gg][ri]);
    }
    barrier_lgkm();

    // ---- P4: C finalize -> s_pre ----
    {
      const int r=tid>>8, jj=tid&255;
      float s0=s_part[0][0][r][jj]+s_part[1][0][r][jj]+s_part[2][0][r][jj]+s_part[3][0][r][jj];
      float s1=s_part[0][1][r][jj]+s_part[1][1][r][jj]+s_part[2][1][r][jj]+s_part[3][1][r][jj];
      float s2=s_part[0][2][r][jj]+s_part[1][2][r][jj]+s_part[2][2][r][jj]+s_part[3][2][r][jj];
      float s3=s_part[0][3][r][jj]+s_part[1][3][r][jj]+s_part[2][3][r][jj]+s_part[3][3][r][jj];
      float s4=s_part[0][4][r][jj]+s_part[1][4][r][jj]+s_part[2][4][r][jj]+s_part[3][4][r][jj];
      float s5=s_part[0][5][r][jj]+s_part[1][5][r][jj]+s_part[2][5][r][jj]+s_part[3][5][r][jj];
      float r_ = sigm(s0+sb[OFF_BIH+jj]     + s3+sb[OFF_BHH+jj]);
      float z_ = sigm(s1+sb[OFF_BIH+256+jj] + s4+sb[OFF_BHH+256+jj]);
      float n_ = tanh_f(s2+sb[OFF_BIH+512+jj] + r_*(s5+sb[OFF_BHH+512+jj]));
      s_pre[r][jj] = (1.f - z_)*n_ + z_*s_h[r][jj];
    }
    barrier_lgkm();

    // ---- P5: LayerNorm + rho/phi ----
    ln_rp(OFF_WRP, OFF_BRP);
    barrier_lgkm();

    // ---- P6: E partials (Wg x h_new), 16-way k-split ----
    {
      f32x2 acc[ROWS];
      #pragma unroll
      for (int ri=0;ri<ROWS;ri++) acc[ri]=(f32x2){0.f,0.f};
      const int kb = w*4;
      #pragma unroll
      for (int q=0;q<4;q++){
        float4 wv = tg[(kb+q)*64 + j6];
        #pragma unroll
        for (int ri=0;ri<ROWS;ri++){
          float4 ah=*(const float4*)&s_h[ri][(kb+q)<<2];
          fma4p(acc[ri],ah,wv);
        }
      }
      #pragma unroll
      for (int ri=0;ri<ROWS;ri++) s_part[w>>2][0][ri][(w&3)*64 + j6] = hadd(acc[ri]);
    }
    barrier_lgkm();

    // ---- P7: FA — K finalize + rotate + Kalman update + next feat ----
    if (tid < 256){
      float kacc = sb[OFF_BG+pd];
      #pragma unroll
      for (int q=0;q<16;q++) kacc += s_part[q>>2][0][pr][(q&3)*64+pd];
      float kg = sigm(kacc);
      float rho=s_rho[pr], phi=s_phi[pr];
      float sn,cs; __sincosf(phi,&sn,&cs);
      float px = __shfl_xor(x_st,32);
      float pre = (pd<32) ? rho*(cs*x_st - sn*px) : rho*(sn*px + cs*x_st);
      float del = kg*(y_cur - pre);
      x_st = pre + del;
      s_x[pr][pd] = x_st;
      s_feat[pr][pd]      = y_next - y_cur;
      s_feat[pr][64+pd]   = y_next - x_st;
      s_feat[pr][128+pd]  = del;
      y_cur = y_next;
    }
    barrier_lgkm();
  }

  // ======================= ROLLOUT: 32 steps =======================
  #pragma unroll 1
  for (int u=0; u<WOUT; ++u){
    // ---- R-P1: all 6 gate partials ----
    {
      f32x2 a[6][ROWS];
      #pragma unroll
      for (int gg=0;gg<6;gg++)
        #pragma unroll
        for (int ri=0;ri<ROWS;ri++) a[gg][ri]=(f32x2){0.f,0.f};
      if (g4 < 3){
        const int k0i=g4*20;
        #pragma unroll 2
        for (int k4=k0i;k4<k0i+20;k4++){
          const int base=k4*768 + j256;
          float4 wir=tir[base], wiz=tir[base+256], win=tir[base+512];
          #pragma unroll
          for (int ri=0;ri<ROWS;ri++){
            float4 ah=*(const float4*)&s_h[ri][k4<<2];
            fma4p(a[0][ri],ah,wir); fma4p(a[1][ri],ah,wiz); fma4p(a[2][ri],ah,win);
          }
        }
      } else {
        #pragma unroll
        for (int k4=60;k4<64;k4++){
          const int base=k4*768 + j256;
          float4 wir=tir[base], wiz=tir[base+256], win=tir[base+512];
          #pragma unroll
          for (int ri=0;ri<ROWS;ri++){
            float4 ah=*(const float4*)&s_h[ri][k4<<2];
            fma4p(a[0][ri],ah,wir); fma4p(a[1][ri],ah,wiz); fma4p(a[2][ri],ah,win);
          }
        }
        #pragma unroll 2
        for (int k4=64;k4<80;k4++){
          const int base=k4*768 + j256;
          float4 wir=tir[base], wiz=tir[base+256], win=tir[base+512];
          #pragma unroll
          for (int ri=0;ri<ROWS;ri++){
            float4 ax=*(const float4*)&s_x[ri][(k4-64)<<2];
            fma4p(a[0][ri],ax,wir); fma4p(a[1][ri],ax,wiz); fma4p(a[2][ri],ax,win);
          }
        }
      }
      {
        #pragma unroll 2
        for (int k4=k0C;k4<k0C+16;k4++){
          const int base=k4*768 + j256;
          float4 whr=th2[base], whz=th2[base+256], whn=th2[base+512];
          #pragma unroll
          for (int ri=0;ri<ROWS;ri++){
            float4 ah=*(const float4*)&s_h[ri][k4<<2];
            fma4p(a[3][ri],ah,whr); fma4p(a[4][ri],ah,whz); fma4p(a[5][ri],ah,whn);
          }
        }
      }
      #pragma unroll
      for (int gg=0;gg<6;gg++)
        #pragma unroll
        for (int ri=0;ri<ROWS;ri++)
          s_part[g4][gg][ri][j256]=hadd(a[gg][ri]);
    }
    barrier_lgkm();

    // ---- R-P2: finalize -> s_pre ----
    {
      const int r=tid>>8, jj=tid&255;
      float s0=s_part[0][0][r][jj]+s_part[1][0][r][jj]+s_part[2][0][r][jj]+s_part[3][0][r][jj];
      float s1=s_part[0][1][r][jj]+s_part[1][1][r][jj]+s_part[2][1][r][jj]+s_part[3][1][r][jj];
      float s2=s_part[0][2][r][jj]+s_part[1][2][r][jj]+s_part[2][2][r][jj]+s_part[3][2][r][jj];
      float s3=s_part[0][3][r][jj]+s_part[1][3][r][jj]+s_part[2][3][r][jj]+s_part[3][3][r][jj];
      float s4=s_part[0][4][r][jj]+s_part[1][4][r][jj]+s_part[2][4][r][jj]+s_part[3][4][r][jj];
      float s5=s_part[0][5][r][jj]+s_part[1][5][r][jj]+s_part[2][5][r][jj]+s_part[3][5][r][jj];
      float r_ = sigm(s0+sb[OFF_BIHR+jj]     + s3+sb[OFF_BHHR+jj]);
      float z_ = sigm(s1+sb[OFF_BIHR+256+jj] + s4+sb[OFF_BHHR+256+jj]);
      float n_ = tanh_f(s2+sb[OFF_BIHR+512+jj] + r_*(s5+sb[OFF_BHHR+512+jj]));
      s_pre[r][jj] = (1.f - z_)*n_ + z_*s_h[r][jj];
    }
    barrier_lgkm();

    // ---- R-P3: LayerNorm + rho/phi ----
    ln_rp(OFF_WRPR, OFF_BRPR);
    barrier_lgkm();

    // ---- R-P4: rotate curr, emit ----
    if (tid < 256){
      float rho=s_rho[pr], phi=s_phi[pr];
      float sn,cs; __sincosf(phi,&sn,&cs);
      float px = __shfl_xor(x_st,32);
      float nx = (pd<32) ? rho*(cs*x_st - sn*px) : rho*(sn*px + cs*x_st);
      x_st = nx;
      s_x[pr][pd] = nx;
      out[(size_t)(gb0+pr)*(WOUT*64) + (size_t)u*64 + pd] = nx;
    }
    barrier_lgkm();
  }
}

extern "C" void kernel_launch(void* const* d_in, const int* in_sizes, int n_in,
                              void* d_out, int out_size, void* d_ws, size_t ws_size,
                              hipStream_t stream){
  const float* x_in = (const float*)d_in[0];
  // d_in[1] = w_out scalar (hardcoded 32)
  const float* Wf   = (const float*)d_in[2];
  const float* bf_  = (const float*)d_in[3];
  const float* Wih  = (const float*)d_in[4];
  const float* Whh  = (const float*)d_in[5];
  const float* bih  = (const float*)d_in[6];
  const float* bhh  = (const float*)d_in[7];
  const float* lng  = (const float*)d_in[8];
  const float* lnb  = (const float*)d_in[9];
  const float* Wg   = (const float*)d_in[10];
  const float* bg   = (const float*)d_in[11];
  const float* Wrp  = (const float*)d_in[12];
  const float* brp  = (const float*)d_in[13];
  const float* Wihr = (const float*)d_in[14];
  const float* Whhr = (const float*)d_in[15];
  const float* bihr = (const float*)d_in[16];
  const float* bhhr = (const float*)d_in[17];
  const float* Wrpr = (const float*)d_in[18];
  const float* brpr = (const float*)d_in[19];

  float* ws = (float*)d_ws;
  float* t_wf   = ws;             // 49152
  float* t_wih  = ws + 49152;     // 196608
  float* t_whh  = ws + 245760;    // 196608
  float* t_wg   = ws + 442368;    // 16384
  float* t_wihr = ws + 458752;    // 245760
  float* t_whhr = ws + 704512;    // 196608  (end: 901120 floats = 3.44 MB)

  transpose_w<<<(49152 +255)/256, 256, 0, stream>>>(Wf,   t_wf,   256, 192);
  transpose_w<<<(196608+255)/256, 256, 0, stream>>>(Wih,  t_wih,  768, 256);
  transpose_w<<<(196608+255)/256, 256, 0, stream>>>(Whh,  t_whh,  768, 256);
  transpose_w<<<(16384 +255)/256, 256, 0, stream>>>(Wg,   t_wg,   64,  256);
  transpose_w<<<(245760+255)/256, 256, 0, stream>>>(Wihr, t_wihr, 768, 320);
  transpose_w<<<(196608+255)/256, 256, 0, stream>>>(Whhr, t_whhr, 768, 256);

  knet_v9<<<256, 1024, 0, stream>>>(x_in, t_wf, t_wih, t_whh, t_wg, t_wihr, t_whhr,
      bf_, bih, bhh, lng, lnb, bg, Wrp, brp, bihr, bhhr, Wrpr, brpr,
      (float*)d_out);
}